// Round 15
// baseline (77.878 us; speedup 1.0000x reference)
//
#include <hip/hip_runtime.h>
#include <cmath>

#define B_   2
#define C_   256
#define HC_  128
#define DC_  3
#define H_   48
#define W_   48
#define HW_  (H_ * W_)      // 2304
#define NP_  (B_ * HW_)     // 4608
#define K_   (DC_ * 49)     // 147
#define GW   64             // padded g width (col = x+3, 16B-aligned rows)
#define SST  19             // S stride (words)

typedef unsigned short ush;
typedef __attribute__((ext_vector_type(8))) short bf16x8;
typedef __attribute__((ext_vector_type(8))) unsigned short ush8x;
typedef __attribute__((ext_vector_type(4))) float f32x4;
typedef __attribute__((ext_vector_type(4))) unsigned u32x4;

__device__ inline ush f2bf(float f) {
    union { float f; unsigned u; } v; v.f = f;
    unsigned r = v.u + 0x7FFF + ((v.u >> 16) & 1);
    return (ush)(r >> 16);
}
__device__ inline float bf2f(ush h) {
    union { unsigned u; float f; } v; v.u = ((unsigned)h) << 16;
    return v.f;
}
__device__ inline unsigned packhl(float f) {
    ush h = f2bf(f);
    ush l = f2bf(f - bf2f(h));
    return (unsigned)h | ((unsigned)l << 16);
}
__device__ __forceinline__ void gload16(const void* g, void* l) {
    __builtin_amdgcn_global_load_lds(
        (const __attribute__((address_space(1))) unsigned*)g,
        (__attribute__((address_space(3))) unsigned*)l, 16, 0, 0);
}

// ---------------------------------------------------------------------------
// 0) prep: transpose+split ctx/x; weight hi/lo split. (unchanged)
__global__ __launch_bounds__(256) void prep_kernel(
    const float* __restrict__ ctx, const float* __restrict__ x,
    const float* __restrict__ psi_w, const float* __restrict__ g_w,
    const float* __restrict__ theta_w, const float* __restrict__ Ww,
    ush* __restrict__ ctxTH, ush* __restrict__ ctxTL,
    ush* __restrict__ xTH, ush* __restrict__ xTL,
    ush* __restrict__ WpgH, ush* __restrict__ WpgL,
    ush* __restrict__ WqH, ush* __restrict__ WqL,
    ush* __restrict__ WwH, ush* __restrict__ WwL)
{
    __shared__ float T[64][65];
    int id = blockIdx.x;
    if (id >= 1152) {
        int idx = ((id - 1152) * 256 + threadIdx.x) * 4;
        float4 v;
        ush *dH, *dL;
        if (idx < 65536) {
            v = *(const float4*)(idx < 32768 ? psi_w + idx : g_w + (idx - 32768));
            dH = WpgH + idx; dL = WpgL + idx;
        } else if (idx < 98304) {
            v = *(const float4*)(theta_w + idx - 65536);
            dH = WqH + idx - 65536; dL = WqL + idx - 65536;
        } else {
            v = *(const float4*)(Ww + idx - 98304);
            dH = WwH + idx - 98304; dL = WwL + idx - 98304;
        }
        ushort4 h, l;
        h.x = f2bf(v.x); l.x = f2bf(v.x - bf2f(h.x));
        h.y = f2bf(v.y); l.y = f2bf(v.y - bf2f(h.y));
        h.z = f2bf(v.z); l.z = f2bf(v.z - bf2f(h.z));
        h.w = f2bf(v.w); l.w = f2bf(v.w - bf2f(h.w));
        *(ushort4*)dH = h; *(ushort4*)dL = l;
        return;
    }
    const float* src;
    ush *dH, *dL;
    size_t rowStride;
    if (id < 864) {
        int ct = id & 3, pt = (id >> 2) % 36, bd = id / 144;
        int b = bd / 3, d = bd % 3;
        int c0 = ct * 64, p0 = pt * 64;
        src = ctx + ((size_t)(b * 256 + c0) * 3 + d) * HW_ + p0;
        rowStride = 3 * HW_;
        size_t ob = ((size_t)(b * 3 + d) * HW_ + p0) * 256 + c0;
        dH = ctxTH + ob; dL = ctxTL + ob;
    } else {
        int id2 = id - 864;
        int ct = id2 & 3, pt = (id2 >> 2) % 36, b = id2 / 144;
        int c0 = ct * 64, p0 = pt * 64;
        src = x + (size_t)(b * 256 + c0) * HW_ + p0;
        rowStride = HW_;
        size_t ob = ((size_t)b * HW_ + p0) * 256 + c0;
        dH = xTH + ob; dL = xTL + ob;
    }
    int t = threadIdx.x;
    int cl = t >> 4, p4 = (t & 15) * 4;
    #pragma unroll
    for (int r = 0; r < 4; ++r) {
        int c = cl + r * 16;
        float4 v = *(const float4*)(src + (size_t)c * rowStride + p4);
        T[c][p4] = v.x; T[c][p4 + 1] = v.y; T[c][p4 + 2] = v.z; T[c][p4 + 3] = v.w;
    }
    __syncthreads();
    int pl = t >> 2, ch = t & 3;
    #pragma unroll
    for (int s = 0; s < 2; ++s) {
        int c8 = (ch + s * 4) * 8;
        ush8x vh, vl;
        #pragma unroll
        for (int i = 0; i < 8; ++i) {
            float f = T[c8 + i][pl];
            ush hh = f2bf(f);
            vh[i] = hh;
            vl[i] = f2bf(f - bf2f(hh));
        }
        *(ush8x*)(dH + (size_t)pl * 256 + c8) = vh;
        *(ush8x*)(dL + (size_t)pl * 256 + c8) = vl;
    }
}

// ---------------------------------------------------------------------------
// 1) proj4 (unchanged)
__global__ __launch_bounds__(256) void proj4_kernel(
    const ush* __restrict__ WpgH, const ush* __restrict__ WpgL,
    const ush* __restrict__ WqH, const ush* __restrict__ WqL,
    const ush* __restrict__ ctxTH, const ush* __restrict__ ctxTL,
    const ush* __restrict__ xTH, const ush* __restrict__ xTL,
    ush* __restrict__ psiH, ush* __restrict__ psiL,
    ush* __restrict__ gtmp, ush* __restrict__ qH, ush* __restrict__ qL)
{
    __shared__ __align__(16) unsigned char LB[32768];

    int bid = blockIdx.x;
    int swz = (bid & 7) * 126 + (bid >> 3);
    int t = threadIdx.x, w = t >> 6, l = t & 63, lc = l & 15, grp = l >> 4;
    int mode, b, d, pxBase, otg;
    const ush *XH, *XL, *WH, *WL;
    if (swz < 864) {
        mode = 0; otg = swz & 3;
        int rest = swz >> 2;
        int pxt = rest % 36, bd = rest / 36;
        b = bd / 3; d = bd % 3;
        pxBase = pxt * 64;
        size_t xb = (size_t)(b * 3 + d) * HW_ * 256;
        XH = ctxTH + xb; XL = ctxTL + xb;
        WH = WpgH; WL = WpgL;
    } else {
        mode = 1;
        int id2 = swz - 864; otg = id2 & 1;
        int rest = id2 >> 1;
        int pxt = rest % 36; b = rest / 36; d = 0;
        pxBase = pxt * 64;
        size_t xb = (size_t)b * HW_ * 256;
        XH = xTH + xb; XL = xTL + xb;
        WH = WqH; WL = WqL;
    }

    const ush* GSRC = (w == 0) ? WH : (w == 1) ? WL : (w == 2) ? XH : XL;
    int rowBase = (w < 2) ? (otg * 64) : pxBase;
    int r8 = l >> 3;
    int kg = (l & 7) ^ r8;
    unsigned char* ldsPlane = LB + w * 8192;

    f32x4 acc0 = {0,0,0,0}, acc1 = {0,0,0,0}, acc2 = {0,0,0,0}, acc3 = {0,0,0,0};

    for (int kst = 0; kst < 4; ++kst) {
        __syncthreads();
        #pragma unroll
        for (int wl = 0; wl < 8; ++wl) {
            int row = rowBase + wl * 8 + r8;
            gload16(GSRC + (size_t)row * 256 + kst * 64 + kg * 8,
                    ldsPlane + wl * 1024);
        }
        __syncthreads();

        #pragma unroll
        for (int ksub = 0; ksub < 2; ++ksub) {
            int sw = ((ksub * 4 + grp) ^ (lc & 7)) << 4;
            int brow = w * 16 + lc;
            bf16x8 bh = *(const bf16x8*)(LB + 16384 + brow * 128 + sw);
            bf16x8 bl = *(const bf16x8*)(LB + 24576 + brow * 128 + sw);
            #pragma unroll
            for (int ot = 0; ot < 4; ++ot) {
                int arow = ot * 16 + lc;
                bf16x8 ah = *(const bf16x8*)(LB +        arow * 128 + sw);
                bf16x8 al = *(const bf16x8*)(LB + 8192 + arow * 128 + sw);
                f32x4 a = (ot == 0) ? acc0 : (ot == 1) ? acc1 : (ot == 2) ? acc2 : acc3;
                a = __builtin_amdgcn_mfma_f32_16x16x32_bf16(ah, bh, a, 0, 0, 0);
                a = __builtin_amdgcn_mfma_f32_16x16x32_bf16(ah, bl, a, 0, 0, 0);
                a = __builtin_amdgcn_mfma_f32_16x16x32_bf16(al, bh, a, 0, 0, 0);
                if (ot == 0) acc0 = a; else if (ot == 1) acc1 = a;
                else if (ot == 2) acc2 = a; else acc3 = a;
            }
        }
    }

    __syncthreads();
    unsigned (*T)[68] = (unsigned(*)[68])LB;
    {
        u32x4 pv;
        pv[0] = packhl(acc0[0]); pv[1] = packhl(acc0[1]);
        pv[2] = packhl(acc0[2]); pv[3] = packhl(acc0[3]);
        *(u32x4*)&T[w * 16 + lc][0 * 16 + grp * 4] = pv;
        pv[0] = packhl(acc1[0]); pv[1] = packhl(acc1[1]);
        pv[2] = packhl(acc1[2]); pv[3] = packhl(acc1[3]);
        *(u32x4*)&T[w * 16 + lc][1 * 16 + grp * 4] = pv;
        pv[0] = packhl(acc2[0]); pv[1] = packhl(acc2[1]);
        pv[2] = packhl(acc2[2]); pv[3] = packhl(acc2[3]);
        *(u32x4*)&T[w * 16 + lc][2 * 16 + grp * 4] = pv;
        pv[0] = packhl(acc3[0]); pv[1] = packhl(acc3[1]);
        pv[2] = packhl(acc3[2]); pv[3] = packhl(acc3[3]);
        *(u32x4*)&T[w * 16 + lc][3 * 16 + grp * 4] = pv;
    }
    __syncthreads();

    if (mode == 1 || otg < 2) {
        ush* PH = (mode == 0) ? psiH : qH;
        ush* PL = (mode == 0) ? psiL : qL;
        #pragma unroll
        for (int it = 0; it < 2; ++it) {
            int idx = it * 256 + t;
            int pxl = idx >> 3, ch = idx & 7;
            u32x4 v0 = *(const u32x4*)&T[pxl][ch * 8];
            u32x4 v1 = *(const u32x4*)&T[pxl][ch * 8 + 4];
            ush8x hi, lo;
            #pragma unroll
            for (int i = 0; i < 4; ++i) {
                hi[i] = (ush)(v0[i] & 0xffffu); lo[i] = (ush)(v0[i] >> 16);
                hi[4 + i] = (ush)(v1[i] & 0xffffu); lo[4 + i] = (ush)(v1[i] >> 16);
            }
            int pix = pxBase + pxl;
            size_t base;
            if (mode == 0)
                base = ((size_t)(b * DC_ + d) * HW_ + pix) * HC_ + otg * 64 + ch * 8;
            else
                base = ((size_t)b * HW_ + pix) * HC_ + otg * 64 + ch * 8;
            *(ush8x*)&PH[base] = hi;
            *(ush8x*)&PL[base] = lo;
        }
    } else {
        #pragma unroll
        for (int it = 0; it < 2; ++it) {
            int idx = it * 256 + t;
            int ol = idx >> 3, pg = idx & 7;
            ush8x hv;
            #pragma unroll
            for (int i = 0; i < 8; ++i)
                hv[i] = (ush)(T[pg * 8 + i][ol] & 0xffffu);
            int og = (otg - 2) * 64 + ol;
            int pxg = pxBase + pg * 8;
            int yy = pxg / W_, xx = pxg - yy * W_;
            *(ush8x*)&gtmp[(((size_t)(b * HC_ + og) * DC_ + d) * H_ + yy) * W_ + xx] = hv;
        }
    }
}

// ---------------------------------------------------------------------------
// 1b) pad (unchanged)
__global__ __launch_bounds__(256) void pad2_kernel(
    const ush* __restrict__ gtmp, ush* __restrict__ gB)
{
    __shared__ ush R[32][48];
    int blk = blockIdx.x, t = threadIdx.x;
    int r = t >> 3, ch = t & 7;
    size_t row = (size_t)blk * 32 + r;
    if (ch < 6)
        *(ush8x*)&R[r][ch * 8] = *(const ush8x*)&gtmp[row * W_ + ch * 8];
    __syncthreads();
    ush8x o;
    #pragma unroll
    for (int i = 0; i < 8; ++i) {
        int x = ch * 8 + i - 3;
        x = min(max(x, 0), W_ - 1);
        o[i] = R[r][x];
    }
    *(ush8x*)&gB[row * GW + ch * 8] = o;
}

// ---------------------------------------------------------------------------
// 2a) scores: grid 864 = tile(288) x d(3). 4 waves compute S_d[49x16] -> Sg.
__global__ __launch_bounds__(256) void scores_kernel(
    const ush* __restrict__ qHp, const ush* __restrict__ qLp,
    const ush* __restrict__ psiHp, const ush* __restrict__ psiLp,
    float* __restrict__ Sg)
{
    __shared__ float S[49 * SST];

    int bid = blockIdx.x;
    int swz = (bid & 7) * 108 + (bid >> 3);   // 864 = 8*108
    int tile = swz / 3, d = swz - 3 * tile;
    int b = tile / 144;
    int tr = tile - b * 144;
    int y0 = tr / 3;
    int x0 = (tr % 3) * 16;

    int t = threadIdx.x;
    int w = t >> 6, l = t & 63, lc = l & 15, grp = l >> 4;
    int pixBase = b * HW_ + y0 * W_ + x0;

    const ush* qrowH = qHp + (size_t)(pixBase + lc) * HC_ + grp * 8;
    const ush* qrowL = qLp + (size_t)(pixBase + lc) * HC_ + grp * 8;
    bf16x8 qh[4], ql[4];
    #pragma unroll
    for (int ks = 0; ks < 4; ++ks) {
        qh[ks] = *(const bf16x8*)(qrowH + ks * 32);
        ql[ks] = *(const bf16x8*)(qrowL + ks * 32);
    }

    size_t dOff = (size_t)(b * DC_ + d) * HW_ * HC_;
    for (int j = w; j < 14; j += 4) {
        int i = j >> 1, f = j & 1;
        int ry = min(max(y0 + i - 3, 0), H_ - 1);
        const ush* psiRowH = psiHp + dOff + (size_t)ry * W_ * HC_;
        const ush* psiRowL = psiLp + dOff + (size_t)ry * W_ * HC_;
        int c = f * 16 + lc;
        int px = min(max(x0 + c - 3, 0), W_ - 1);
        const ush* bpH = psiRowH + (size_t)px * HC_ + grp * 8;
        const ush* bpL = psiRowL + (size_t)px * HC_ + grp * 8;
        bf16x8 ph[4], pl[4];
        #pragma unroll
        for (int ks = 0; ks < 4; ++ks) {
            ph[ks] = *(const bf16x8*)(bpH + ks * 32);
            pl[ks] = *(const bf16x8*)(bpL + ks * 32);
        }
        f32x4 acc = {0.f, 0.f, 0.f, 0.f};
        #pragma unroll
        for (int ks = 0; ks < 4; ++ks) {
            acc = __builtin_amdgcn_mfma_f32_16x16x32_bf16(qh[ks], ph[ks], acc, 0, 0, 0);
            acc = __builtin_amdgcn_mfma_f32_16x16x32_bf16(qh[ks], pl[ks], acc, 0, 0, 0);
            acc = __builtin_amdgcn_mfma_f32_16x16x32_bf16(ql[ks], ph[ks], acc, 0, 0, 0);
        }
        #pragma unroll
        for (int r = 0; r < 4; ++r) {
            int pp = grp * 4 + r;
            int j2 = c - pp;
            if (j2 >= 0 && j2 < 7) S[(i * 7 + j2) * SST + pp] = acc[r];
        }
    }
    __syncthreads();

    // coalesced dump: Sg[tile][d][49][16]
    float* dst = Sg + ((size_t)tile * 3 + d) * 784;
    for (int idx = t; idx < 784; idx += 256)
        dst[idx] = S[(idx >> 4) * SST + (idx & 15)];
}

// ---------------------------------------------------------------------------
// 2b) smpv: grid 576 = tile(288) x h-half(2). softmax (redundant per half) +
//     PV for 64 h; Y written coalesced to global hi/lo.
__global__ __launch_bounds__(256) void smpv_kernel(
    const float* __restrict__ Sg, const ush* __restrict__ g,
    ush* __restrict__ yH, ush* __restrict__ yL)
{
    __shared__ float S[147 * SST];
    __shared__ ush YS[2][16][72];

    int bid = blockIdx.x;
    int swz = (bid & 7) * 72 + (bid >> 3);    // 576 = 8*72
    int tile = swz >> 1, hh = swz & 1;
    int b = tile / 144;
    int tr = tile - b * 144;
    int y0 = tr / 3;
    int x0 = (tr % 3) * 16;

    int t = threadIdx.x;
    int w = t >> 6, l = t & 63, lc = l & 15, grp = l >> 4;
    int pixBase = b * HW_ + y0 * W_ + x0;

    const float* Ssrc = Sg + (size_t)tile * 2352;
    for (int idx = t; idx < 2352; idx += 256)
        S[(idx >> 4) * SST + (idx & 15)] = Ssrc[idx];
    __syncthreads();

    // softmax: 4 waves x 4 px
    #pragma unroll
    for (int pi = 0; pi < 4; ++pi) {
        int p = w * 4 + pi;
        float s0 = S[l * SST + p];
        float s1 = S[(64 + l) * SST + p];
        float s2 = (l + 128 < K_) ? S[(128 + l) * SST + p] : -1e30f;
        float m = fmaxf(fmaxf(s0, s1), s2);
        #pragma unroll
        for (int off = 32; off; off >>= 1) m = fmaxf(m, __shfl_xor(m, off));
        float e0 = __expf(s0 - m), e1 = __expf(s1 - m), e2 = __expf(s2 - m);
        float sum = e0 + e1 + e2;
        #pragma unroll
        for (int off = 32; off; off >>= 1) sum += __shfl_xor(sum, off);
        float inv = 1.0f / sum;
        S[l * SST + p] = e0 * inv;
        S[(64 + l) * SST + p] = e1 * inv;
        if (l + 128 < K_) S[(128 + l) * SST + p] = e2 * inv;
    }
    __syncthreads();

    // PV: h = hh*64 + w*16 + lc, double-buffered g row prefetch
    int hl = w * 16 + lc;
    int hB = hh * 64 + hl;
    const ush* gBase = g + (size_t)(b * HC_ + hB) * DC_ * H_ * GW + x0 + grp * 8;
    bf16x8 bgb[2][7];
    #pragma unroll
    for (int i = 0; i < 7; ++i) {
        int ry = min(max(y0 + i - 3, 0), H_ - 1);
        bgb[0][i] = *(const bf16x8*)(gBase + (size_t)ry * GW);
    }
    f32x4 acc = {0.f, 0.f, 0.f, 0.f};
    #pragma unroll
    for (int d = 0; d < 3; ++d) {
        if (d < 2) {
            #pragma unroll
            for (int i = 0; i < 7; ++i) {
                int ry = min(max(y0 + i - 3, 0), H_ - 1);
                bgb[(d + 1) & 1][i] = *(const bf16x8*)(gBase + (size_t)((d + 1) * H_ + ry) * GW);
            }
        }
        #pragma unroll
        for (int i = 0; i < 7; ++i) {
            int idx = d * 7 + i;
            unsigned au[4];
            #pragma unroll
            for (int rr = 0; rr < 4; ++rr) {
                int k0 = grp * 8 + rr * 2;
                int j0 = k0 - lc, j1 = k0 + 1 - lc;
                float v0 = (j0 >= 0 && j0 < 7) ? S[(idx * 7 + j0) * SST + lc] : 0.f;
                float v1 = (j1 >= 0 && j1 < 7) ? S[(idx * 7 + j1) * SST + lc] : 0.f;
                au[rr] = (unsigned)f2bf(v0) | ((unsigned)f2bf(v1) << 16);
            }
            union { unsigned u[4]; bf16x8 v; } af;
            af.u[0] = au[0]; af.u[1] = au[1]; af.u[2] = au[2]; af.u[3] = au[3];
            acc = __builtin_amdgcn_mfma_f32_16x16x32_bf16(af.v, bgb[d & 1][i], acc, 0, 0, 0);
        }
    }
    #pragma unroll
    for (int r = 0; r < 4; ++r) {
        int p = grp * 4 + r;
        float v = acc[r];
        ush hv = f2bf(v);
        YS[0][p][hl] = hv;
        YS[1][p][hl] = f2bf(v - bf2f(hv));
    }
    __syncthreads();

    // coalesced Y dump: 2 planes x 16 px x 8 chunks of 8 h
    {
        int plane = t >> 7, r2 = t & 127;
        int px = r2 >> 3, ch = r2 & 7;
        ush8x v;
        #pragma unroll
        for (int i = 0; i < 8; ++i) v[i] = YS[plane][px][ch * 8 + i];
        ush* dst = (plane ? yL : yH) + (size_t)(pixBase + px) * HC_ + hh * 64 + ch * 8;
        *(ush8x*)dst = v;
    }
}

// ---------------------------------------------------------------------------
// 2c) wy GEMM (proj4-style DMA staging): M=256, K=128, N=4608.
//     Block = 64 out x 64 px, 2 ksteps of 64. grid 288 = 4 otg x 72 pxt.
__global__ __launch_bounds__(256) void wy_gemm_kernel(
    const ush* __restrict__ WwH, const ush* __restrict__ WwL,
    const ush* __restrict__ yHp, const ush* __restrict__ yLp,
    float* __restrict__ wyO)
{
    __shared__ __align__(16) unsigned char LB[32768];

    int bid = blockIdx.x;
    int swz = (bid & 7) * 36 + (bid >> 3);    // 288 = 8*36
    int otg = swz & 3, pxt = swz >> 2;
    int pxBase = pxt * 64;
    int b = pxBase / HW_;
    int pBase = pxBase - b * HW_;

    int t = threadIdx.x, w = t >> 6, l = t & 63, lc = l & 15, grp = l >> 4;
    const ush* GSRC = (w == 0) ? WwH : (w == 1) ? WwL : (w == 2) ? yHp : yLp;
    int rowBase = (w < 2) ? (otg * 64) : pxBase;
    int r8 = l >> 3;
    int kg = (l & 7) ^ r8;
    unsigned char* ldsPlane = LB + w * 8192;

    f32x4 acc0 = {0,0,0,0}, acc1 = {0,0,0,0}, acc2 = {0,0,0,0}, acc3 = {0,0,0,0};

    for (int kst = 0; kst < 2; ++kst) {
        __syncthreads();
        #pragma unroll
        for (int wl = 0; wl < 8; ++wl) {
            int row = rowBase + wl * 8 + r8;
            gload16(GSRC + (size_t)row * 128 + kst * 64 + kg * 8,
                    ldsPlane + wl * 1024);
        }
        __syncthreads();

        #pragma unroll
        for (int ksub = 0; ksub < 2; ++ksub) {
            int sw = ((ksub * 4 + grp) ^ (lc & 7)) << 4;
            int brow = w * 16 + lc;
            bf16x8 bh = *(const bf16x8*)(LB + 16384 + brow * 128 + sw);
            bf16x8 bl = *(const bf16x8*)(LB + 24576 + brow * 128 + sw);
            #pragma unroll
            for (int ot = 0; ot < 4; ++ot) {
                int arow = ot * 16 + lc;
                bf16x8 ah = *(const bf16x8*)(LB +        arow * 128 + sw);
                bf16x8 al = *(const bf16x8*)(LB + 8192 + arow * 128 + sw);
                f32x4 a = (ot == 0) ? acc0 : (ot == 1) ? acc1 : (ot == 2) ? acc2 : acc3;
                a = __builtin_amdgcn_mfma_f32_16x16x32_bf16(ah, bh, a, 0, 0, 0);
                a = __builtin_amdgcn_mfma_f32_16x16x32_bf16(ah, bl, a, 0, 0, 0);
                a = __builtin_amdgcn_mfma_f32_16x16x32_bf16(al, bh, a, 0, 0, 0);
                if (ot == 0) acc0 = a; else if (ot == 1) acc1 = a;
                else if (ot == 2) acc2 = a; else acc3 = a;
            }
        }
    }

    int p = pBase + w * 16 + lc;
    #pragma unroll
    for (int ot = 0; ot < 4; ++ot) {
        f32x4 a = (ot == 0) ? acc0 : (ot == 1) ? acc1 : (ot == 2) ? acc2 : acc3;
        int o0 = otg * 64 + ot * 16 + grp * 4;
        #pragma unroll
        for (int r = 0; r < 4; ++r)
            wyO[(size_t)(b * C_ + o0 + r) * HW_ + p] = a[r];
    }
}

// ---------------------------------------------------------------------------
// 3) BN batch stats (unchanged)
__global__ __launch_bounds__(256) void bn_stats_kernel(
    const float* __restrict__ wy, const float* __restrict__ gamma,
    const float* __restrict__ beta, float2* __restrict__ stats)
{
    int o = blockIdx.x;
    int tid = threadIdx.x;
    float s = 0.f, s2 = 0.f;
    for (int idx = tid; idx < NP_; idx += 256) {
        int b = idx / HW_;
        int p = idx - b * HW_;
        float v = wy[(size_t)(b * C_ + o) * HW_ + p];
        s += v;
        s2 = fmaf(v, v, s2);
    }
    #pragma unroll
    for (int off = 32; off; off >>= 1) {
        s  += __shfl_xor(s, off);
        s2 += __shfl_xor(s2, off);
    }
    __shared__ float ls[4], ls2[4];
    int wv = tid >> 6, lane = tid & 63;
    if (lane == 0) { ls[wv] = s; ls2[wv] = s2; }
    __syncthreads();
    if (tid == 0) {
        float S  = ls[0] + ls[1] + ls[2] + ls[3];
        float S2 = ls2[0] + ls2[1] + ls2[2] + ls2[3];
        float mean = S / (float)NP_;
        float var = fmaxf(S2 / (float)NP_ - mean * mean, 0.f);
        float rstd = rsqrtf(var + 1e-5f);
        float sc = gamma[o] * rstd;
        stats[o] = make_float2(sc, beta[o] - mean * sc);
    }
}

// ---------------------------------------------------------------------------
// 4) z = x + wy*scale + shift (unchanged)
__global__ __launch_bounds__(256) void final_kernel(
    const float* __restrict__ x, const float* __restrict__ wy,
    const float2* __restrict__ stats, float* __restrict__ out)
{
    int idx = blockIdx.x * 256 + threadIdx.x;
    int e0 = idx * 4;
    int c = (e0 / HW_) & (C_ - 1);
    float2 st = stats[c];
    float4 xv = *(const float4*)(x + e0);
    float4 wv = *(const float4*)(wy + e0);
    float4 o;
    o.x = fmaf(wv.x, st.x, xv.x + st.y);
    o.y = fmaf(wv.y, st.x, xv.y + st.y);
    o.z = fmaf(wv.z, st.x, xv.z + st.y);
    o.w = fmaf(wv.w, st.x, xv.w + st.y);
    *(float4*)(out + e0) = o;
}

extern "C" void kernel_launch(void* const* d_in, const int* in_sizes, int n_in,
                              void* d_out, int out_size, void* d_ws, size_t ws_size,
                              hipStream_t stream) {
    const float* x       = (const float*)d_in[0];
    const float* ctx     = (const float*)d_in[1];
    const float* theta_w = (const float*)d_in[2];
    const float* psi_w   = (const float*)d_in[3];
    const float* g_w     = (const float*)d_in[4];
    const float* W_w     = (const float*)d_in[5];
    // d_in[6] = W_b: unused, cancels exactly under training-mode BN
    const float* gamma   = (const float*)d_in[7];
    const float* beta    = (const float*)d_in[8];
    float* out = (float*)d_out;

    ush* ws = (ush*)d_ws;
    ush* qH    = ws;                     // 589824
    ush* qL    = qH + 589824;
    ush* psiH  = qL + 589824;            // 1769472
    ush* psiL  = psiH + 1769472;
    ush* gB    = psiL + 1769472;         // 2359296  [B,128,3,48,64] padded
    ush* gtmp  = gB + 2359296;           // 3538944  [B,128,3,48,48] unpadded
    ush* WpgH  = gtmp + 3538944;         // 65536
    ush* WpgL  = WpgH + 65536;
    ush* WqH   = WpgL + 65536;           // 32768
    ush* WqL   = WqH + 32768;
    ush* WwH   = WqL + 32768;            // 32768
    ush* WwL   = WwH + 32768;
    ush* ctxTH = WwL + 32768;            // 3538944
    ush* ctxTL = ctxTH + 3538944;
    ush* xTH   = ctxTL + 3538944;        // 1179648
    ush* xTL   = xTH + 1179648;
    float2* stats = (float2*)(xTL + 1179648);
    // aliases (stream-ordered single-call lifetimes, deterministic each call):
    float* wyB = (float*)ctxTH;          // wy f32 <= ctxT region (dead after proj4)
    float* Sg  = (float*)gtmp;           // scores 2.71MB <= gtmp (dead after pad2)
    ush* yH = xTH;                       // y planes <= xT region (dead after proj4)
    ush* yL = xTH + 589824;

    prep_kernel<<<dim3(1280), 256, 0, stream>>>(ctx, x, psi_w, g_w, theta_w, W_w,
                                                ctxTH, ctxTL, xTH, xTL,
                                                WpgH, WpgL, WqH, WqL, WwH, WwL);
    proj4_kernel<<<dim3(1008), 256, 0, stream>>>(WpgH, WpgL, WqH, WqL,
                                                 ctxTH, ctxTL, xTH, xTL,
                                                 psiH, psiL, gtmp, qH, qL);
    pad2_kernel<<<dim3(1152), 256, 0, stream>>>(gtmp, gB);
    scores_kernel<<<dim3(864), 256, 0, stream>>>(qH, qL, psiH, psiL, Sg);
    smpv_kernel<<<dim3(576), 256, 0, stream>>>(Sg, gB, yH, yL);
    wy_gemm_kernel<<<dim3(288), 256, 0, stream>>>(WwH, WwL, yH, yL, wyB);
    bn_stats_kernel<<<dim3(C_), 256, 0, stream>>>(wyB, gamma, beta, stats);
    final_kernel<<<dim3(B_ * C_ * HW_ / 4 / 256), 256, 0, stream>>>(x, wyB, stats, out);
}

// Round 16
// 69.259 us; speedup vs baseline: 1.1244x; 1.1244x over previous
//
#include <hip/hip_runtime.h>
#include <cmath>

#define B_   2
#define C_   256
#define HC_  128
#define DC_  3
#define H_   48
#define W_   48
#define HW_  (H_ * W_)      // 2304
#define NP_  (B_ * HW_)     // 4608
#define K_   (DC_ * 49)     // 147
#define GW   64             // padded g width (col = x+3, 16B-aligned rows)
#define SST  19             // S stride (words) in smpv

typedef unsigned short ush;
typedef __attribute__((ext_vector_type(8))) short bf16x8;
typedef __attribute__((ext_vector_type(8))) unsigned short ush8x;
typedef __attribute__((ext_vector_type(4))) float f32x4;
typedef __attribute__((ext_vector_type(4))) unsigned u32x4;

__device__ inline ush f2bf(float f) {
    union { float f; unsigned u; } v; v.f = f;
    unsigned r = v.u + 0x7FFF + ((v.u >> 16) & 1);
    return (ush)(r >> 16);
}
__device__ inline float bf2f(ush h) {
    union { unsigned u; float f; } v; v.u = ((unsigned)h) << 16;
    return v.f;
}
__device__ inline unsigned packhl(float f) {
    ush h = f2bf(f);
    ush l = f2bf(f - bf2f(h));
    return (unsigned)h | ((unsigned)l << 16);
}
__device__ __forceinline__ void gload16(const void* g, void* l) {
    __builtin_amdgcn_global_load_lds(
        (const __attribute__((address_space(1))) unsigned*)g,
        (__attribute__((address_space(3))) unsigned*)l, 16, 0, 0);
}

// ---------------------------------------------------------------------------
// 0) prep: transpose+split ctx/x; weight hi/lo split. (unchanged)
__global__ __launch_bounds__(256) void prep_kernel(
    const float* __restrict__ ctx, const float* __restrict__ x,
    const float* __restrict__ psi_w, const float* __restrict__ g_w,
    const float* __restrict__ theta_w, const float* __restrict__ Ww,
    ush* __restrict__ ctxTH, ush* __restrict__ ctxTL,
    ush* __restrict__ xTH, ush* __restrict__ xTL,
    ush* __restrict__ WpgH, ush* __restrict__ WpgL,
    ush* __restrict__ WqH, ush* __restrict__ WqL,
    ush* __restrict__ WwH, ush* __restrict__ WwL)
{
    __shared__ float T[64][65];
    int id = blockIdx.x;
    if (id >= 1152) {
        int idx = ((id - 1152) * 256 + threadIdx.x) * 4;
        float4 v;
        ush *dH, *dL;
        if (idx < 65536) {
            v = *(const float4*)(idx < 32768 ? psi_w + idx : g_w + (idx - 32768));
            dH = WpgH + idx; dL = WpgL + idx;
        } else if (idx < 98304) {
            v = *(const float4*)(theta_w + idx - 65536);
            dH = WqH + idx - 65536; dL = WqL + idx - 65536;
        } else {
            v = *(const float4*)(Ww + idx - 98304);
            dH = WwH + idx - 98304; dL = WwL + idx - 98304;
        }
        ushort4 h, l;
        h.x = f2bf(v.x); l.x = f2bf(v.x - bf2f(h.x));
        h.y = f2bf(v.y); l.y = f2bf(v.y - bf2f(h.y));
        h.z = f2bf(v.z); l.z = f2bf(v.z - bf2f(h.z));
        h.w = f2bf(v.w); l.w = f2bf(v.w - bf2f(h.w));
        *(ushort4*)dH = h; *(ushort4*)dL = l;
        return;
    }
    const float* src;
    ush *dH, *dL;
    size_t rowStride;
    if (id < 864) {
        int ct = id & 3, pt = (id >> 2) % 36, bd = id / 144;
        int b = bd / 3, d = bd % 3;
        int c0 = ct * 64, p0 = pt * 64;
        src = ctx + ((size_t)(b * 256 + c0) * 3 + d) * HW_ + p0;
        rowStride = 3 * HW_;
        size_t ob = ((size_t)(b * 3 + d) * HW_ + p0) * 256 + c0;
        dH = ctxTH + ob; dL = ctxTL + ob;
    } else {
        int id2 = id - 864;
        int ct = id2 & 3, pt = (id2 >> 2) % 36, b = id2 / 144;
        int c0 = ct * 64, p0 = pt * 64;
        src = x + (size_t)(b * 256 + c0) * HW_ + p0;
        rowStride = HW_;
        size_t ob = ((size_t)b * HW_ + p0) * 256 + c0;
        dH = xTH + ob; dL = xTL + ob;
    }
    int t = threadIdx.x;
    int cl = t >> 4, p4 = (t & 15) * 4;
    #pragma unroll
    for (int r = 0; r < 4; ++r) {
        int c = cl + r * 16;
        float4 v = *(const float4*)(src + (size_t)c * rowStride + p4);
        T[c][p4] = v.x; T[c][p4 + 1] = v.y; T[c][p4 + 2] = v.z; T[c][p4 + 3] = v.w;
    }
    __syncthreads();
    int pl = t >> 2, ch = t & 3;
    #pragma unroll
    for (int s = 0; s < 2; ++s) {
        int c8 = (ch + s * 4) * 8;
        ush8x vh, vl;
        #pragma unroll
        for (int i = 0; i < 8; ++i) {
            float f = T[c8 + i][pl];
            ush hh = f2bf(f);
            vh[i] = hh;
            vl[i] = f2bf(f - bf2f(hh));
        }
        *(ush8x*)(dH + (size_t)pl * 256 + c8) = vh;
        *(ush8x*)(dL + (size_t)pl * 256 + c8) = vl;
    }
}

// ---------------------------------------------------------------------------
// 1) proj4 (unchanged)
__global__ __launch_bounds__(256) void proj4_kernel(
    const ush* __restrict__ WpgH, const ush* __restrict__ WpgL,
    const ush* __restrict__ WqH, const ush* __restrict__ WqL,
    const ush* __restrict__ ctxTH, const ush* __restrict__ ctxTL,
    const ush* __restrict__ xTH, const ush* __restrict__ xTL,
    ush* __restrict__ psiH, ush* __restrict__ psiL,
    ush* __restrict__ gtmp, ush* __restrict__ qH, ush* __restrict__ qL)
{
    __shared__ __align__(16) unsigned char LB[32768];

    int bid = blockIdx.x;
    int swz = (bid & 7) * 126 + (bid >> 3);
    int t = threadIdx.x, w = t >> 6, l = t & 63, lc = l & 15, grp = l >> 4;
    int mode, b, d, pxBase, otg;
    const ush *XH, *XL, *WH, *WL;
    if (swz < 864) {
        mode = 0; otg = swz & 3;
        int rest = swz >> 2;
        int pxt = rest % 36, bd = rest / 36;
        b = bd / 3; d = bd % 3;
        pxBase = pxt * 64;
        size_t xb = (size_t)(b * 3 + d) * HW_ * 256;
        XH = ctxTH + xb; XL = ctxTL + xb;
        WH = WpgH; WL = WpgL;
    } else {
        mode = 1;
        int id2 = swz - 864; otg = id2 & 1;
        int rest = id2 >> 1;
        int pxt = rest % 36; b = rest / 36; d = 0;
        pxBase = pxt * 64;
        size_t xb = (size_t)b * HW_ * 256;
        XH = xTH + xb; XL = xTL + xb;
        WH = WqH; WL = WqL;
    }

    const ush* GSRC = (w == 0) ? WH : (w == 1) ? WL : (w == 2) ? XH : XL;
    int rowBase = (w < 2) ? (otg * 64) : pxBase;
    int r8 = l >> 3;
    int kg = (l & 7) ^ r8;
    unsigned char* ldsPlane = LB + w * 8192;

    f32x4 acc0 = {0,0,0,0}, acc1 = {0,0,0,0}, acc2 = {0,0,0,0}, acc3 = {0,0,0,0};

    for (int kst = 0; kst < 4; ++kst) {
        __syncthreads();
        #pragma unroll
        for (int wl = 0; wl < 8; ++wl) {
            int row = rowBase + wl * 8 + r8;
            gload16(GSRC + (size_t)row * 256 + kst * 64 + kg * 8,
                    ldsPlane + wl * 1024);
        }
        __syncthreads();

        #pragma unroll
        for (int ksub = 0; ksub < 2; ++ksub) {
            int sw = ((ksub * 4 + grp) ^ (lc & 7)) << 4;
            int brow = w * 16 + lc;
            bf16x8 bh = *(const bf16x8*)(LB + 16384 + brow * 128 + sw);
            bf16x8 bl = *(const bf16x8*)(LB + 24576 + brow * 128 + sw);
            #pragma unroll
            for (int ot = 0; ot < 4; ++ot) {
                int arow = ot * 16 + lc;
                bf16x8 ah = *(const bf16x8*)(LB +        arow * 128 + sw);
                bf16x8 al = *(const bf16x8*)(LB + 8192 + arow * 128 + sw);
                f32x4 a = (ot == 0) ? acc0 : (ot == 1) ? acc1 : (ot == 2) ? acc2 : acc3;
                a = __builtin_amdgcn_mfma_f32_16x16x32_bf16(ah, bh, a, 0, 0, 0);
                a = __builtin_amdgcn_mfma_f32_16x16x32_bf16(ah, bl, a, 0, 0, 0);
                a = __builtin_amdgcn_mfma_f32_16x16x32_bf16(al, bh, a, 0, 0, 0);
                if (ot == 0) acc0 = a; else if (ot == 1) acc1 = a;
                else if (ot == 2) acc2 = a; else acc3 = a;
            }
        }
    }

    __syncthreads();
    unsigned (*T)[68] = (unsigned(*)[68])LB;
    {
        u32x4 pv;
        pv[0] = packhl(acc0[0]); pv[1] = packhl(acc0[1]);
        pv[2] = packhl(acc0[2]); pv[3] = packhl(acc0[3]);
        *(u32x4*)&T[w * 16 + lc][0 * 16 + grp * 4] = pv;
        pv[0] = packhl(acc1[0]); pv[1] = packhl(acc1[1]);
        pv[2] = packhl(acc1[2]); pv[3] = packhl(acc1[3]);
        *(u32x4*)&T[w * 16 + lc][1 * 16 + grp * 4] = pv;
        pv[0] = packhl(acc2[0]); pv[1] = packhl(acc2[1]);
        pv[2] = packhl(acc2[2]); pv[3] = packhl(acc2[3]);
        *(u32x4*)&T[w * 16 + lc][2 * 16 + grp * 4] = pv;
        pv[0] = packhl(acc3[0]); pv[1] = packhl(acc3[1]);
        pv[2] = packhl(acc3[2]); pv[3] = packhl(acc3[3]);
        *(u32x4*)&T[w * 16 + lc][3 * 16 + grp * 4] = pv;
    }
    __syncthreads();

    if (mode == 1 || otg < 2) {
        ush* PH = (mode == 0) ? psiH : qH;
        ush* PL = (mode == 0) ? psiL : qL;
        #pragma unroll
        for (int it = 0; it < 2; ++it) {
            int idx = it * 256 + t;
            int pxl = idx >> 3, ch = idx & 7;
            u32x4 v0 = *(const u32x4*)&T[pxl][ch * 8];
            u32x4 v1 = *(const u32x4*)&T[pxl][ch * 8 + 4];
            ush8x hi, lo;
            #pragma unroll
            for (int i = 0; i < 4; ++i) {
                hi[i] = (ush)(v0[i] & 0xffffu); lo[i] = (ush)(v0[i] >> 16);
                hi[4 + i] = (ush)(v1[i] & 0xffffu); lo[4 + i] = (ush)(v1[i] >> 16);
            }
            int pix = pxBase + pxl;
            size_t base;
            if (mode == 0)
                base = ((size_t)(b * DC_ + d) * HW_ + pix) * HC_ + otg * 64 + ch * 8;
            else
                base = ((size_t)b * HW_ + pix) * HC_ + otg * 64 + ch * 8;
            *(ush8x*)&PH[base] = hi;
            *(ush8x*)&PL[base] = lo;
        }
    } else {
        #pragma unroll
        for (int it = 0; it < 2; ++it) {
            int idx = it * 256 + t;
            int ol = idx >> 3, pg = idx & 7;
            ush8x hv;
            #pragma unroll
            for (int i = 0; i < 8; ++i)
                hv[i] = (ush)(T[pg * 8 + i][ol] & 0xffffu);
            int og = (otg - 2) * 64 + ol;
            int pxg = pxBase + pg * 8;
            int yy = pxg / W_, xx = pxg - yy * W_;
            *(ush8x*)&gtmp[(((size_t)(b * HC_ + og) * DC_ + d) * H_ + yy) * W_ + xx] = hv;
        }
    }
}

// ---------------------------------------------------------------------------
// 1b) pad (unchanged)
__global__ __launch_bounds__(256) void pad2_kernel(
    const ush* __restrict__ gtmp, ush* __restrict__ gB)
{
    __shared__ ush R[32][48];
    int blk = blockIdx.x, t = threadIdx.x;
    int r = t >> 3, ch = t & 7;
    size_t row = (size_t)blk * 32 + r;
    if (ch < 6)
        *(ush8x*)&R[r][ch * 8] = *(const ush8x*)&gtmp[row * W_ + ch * 8];
    __syncthreads();
    ush8x o;
    #pragma unroll
    for (int i = 0; i < 8; ++i) {
        int x = ch * 8 + i - 3;
        x = min(max(x, 0), W_ - 1);
        o[i] = R[r][x];
    }
    *(ush8x*)&gB[row * GW + ch * 8] = o;
}

// ---------------------------------------------------------------------------
// 2a) scores2: DMA-staged psi/q, pipelined over window rows i.
//     grid 864 = tile(288) x d(3); 4 waves = (f x ks-half); partial S summed
//     at dump. LDS 46KB -> 3 blocks/CU.
__global__ __launch_bounds__(256) void scores2_kernel(
    const ush* __restrict__ qHp, const ush* __restrict__ qLp,
    const ush* __restrict__ psiHp, const ush* __restrict__ psiLp,
    float* __restrict__ Sg)
{
    __shared__ __align__(16) unsigned char QS[8192];       // [plane][16px][16 slots x 16B]
    __shared__ __align__(16) unsigned char PB[2][16384];   // [plane][32px][16 slots x 16B]
    __shared__ float SP[2][49 * 16];

    int bid = blockIdx.x;
    int swz = (bid & 7) * 108 + (bid >> 3);   // 864 = 8*108
    int tile = swz / 3, d = swz - 3 * tile;
    int b = tile / 144;
    int tr = tile - b * 144;
    int y0 = tr / 3;
    int x0 = (tr % 3) * 16;

    int t = threadIdx.x;
    int w = t >> 6, l = t & 63, lc = l & 15, grp = l >> 4;
    int pixBase = b * HW_ + y0 * W_ + x0;
    size_t dOff = (size_t)(b * DC_ + d) * HW_ * HC_;

    // stage q: 512 slots, swizzled source (slot s holds chunk s^(px&7))
    #pragma unroll
    for (int jj = 0; jj < 2; ++jj) {
        int s = jj * 256 + t;
        int plane = s >> 8, rest = s & 255;
        int px = rest >> 4, sl = rest & 15;
        const ush* SRC = plane ? qLp : qHp;
        gload16(SRC + (size_t)(pixBase + px) * HC_ + ((sl ^ (px & 7)) * 8),
                QS + s * 16);
    }

    // psi stage for window row i -> buf
    auto stageP = [&](int i, int buf) {
        int ry = min(max(y0 + i - 3, 0), H_ - 1);
        size_t rowOff = dOff + (size_t)ry * W_ * HC_;
        #pragma unroll
        for (int jj = 0; jj < 4; ++jj) {
            int s = jj * 256 + t;
            int plane = s >> 9, rest = s & 511;
            int pxp = rest >> 4, sl = rest & 15;
            int px = min(max(x0 + pxp - 3, 0), W_ - 1);
            const ush* SRC = plane ? psiLp : psiHp;
            gload16(SRC + rowOff + (size_t)px * HC_ + ((sl ^ (pxp & 7)) * 8),
                    PB[buf] + s * 16);
        }
    };

    stageP(0, 0);
    __syncthreads();   // drains q + psi(0)

    int f = w & 1, kh = w >> 1;
    int c = f * 16 + lc;
    bf16x8 qh[2], ql[2];
    #pragma unroll
    for (int k2 = 0; k2 < 2; ++k2) {
        int K = (kh * 2 + k2) * 4 + grp;
        int s = K ^ (lc & 7);
        qh[k2] = *(const bf16x8*)(QS + (lc * 16 + s) * 16);
        ql[k2] = *(const bf16x8*)(QS + 4096 + (lc * 16 + s) * 16);
    }

    for (int i = 0; i < 7; ++i) {
        if (i < 6) stageP(i + 1, (i + 1) & 1);
        const unsigned char* CB = PB[i & 1];
        f32x4 acc = {0.f, 0.f, 0.f, 0.f};
        #pragma unroll
        for (int k2 = 0; k2 < 2; ++k2) {
            int K = (kh * 2 + k2) * 4 + grp;
            int s = K ^ (c & 7);
            bf16x8 ph = *(const bf16x8*)(CB + (c * 16 + s) * 16);
            bf16x8 pl = *(const bf16x8*)(CB + 8192 + (c * 16 + s) * 16);
            acc = __builtin_amdgcn_mfma_f32_16x16x32_bf16(qh[k2], ph, acc, 0, 0, 0);
            acc = __builtin_amdgcn_mfma_f32_16x16x32_bf16(qh[k2], pl, acc, 0, 0, 0);
            acc = __builtin_amdgcn_mfma_f32_16x16x32_bf16(ql[k2], ph, acc, 0, 0, 0);
        }
        #pragma unroll
        for (int r = 0; r < 4; ++r) {
            int pp = grp * 4 + r;
            int j2 = c - pp;
            if (j2 >= 0 && j2 < 7) SP[kh][(i * 7 + j2) * 16 + pp] = acc[r];
        }
        __syncthreads();   // drains stage(i+1), orders SP/PB
    }

    // dump: Sg[tile][d][49][16] = SP[0] + SP[1]
    float* dst = Sg + ((size_t)tile * 3 + d) * 784;
    for (int idx = t; idx < 784; idx += 256)
        dst[idx] = SP[0][idx] + SP[1][idx];
}

// ---------------------------------------------------------------------------
// 2b) smpv (unchanged): grid 576 = tile x h-half; softmax + PV; Y -> global.
__global__ __launch_bounds__(256) void smpv_kernel(
    const float* __restrict__ Sg, const ush* __restrict__ g,
    ush* __restrict__ yH, ush* __restrict__ yL)
{
    __shared__ float S[147 * SST];
    __shared__ ush YS[2][16][72];

    int bid = blockIdx.x;
    int swz = (bid & 7) * 72 + (bid >> 3);    // 576 = 8*72
    int tile = swz >> 1, hh = swz & 1;
    int b = tile / 144;
    int tr = tile - b * 144;
    int y0 = tr / 3;
    int x0 = (tr % 3) * 16;

    int t = threadIdx.x;
    int w = t >> 6, l = t & 63, lc = l & 15, grp = l >> 4;
    int pixBase = b * HW_ + y0 * W_ + x0;

    const float* Ssrc = Sg + (size_t)tile * 2352;
    for (int idx = t; idx < 2352; idx += 256)
        S[(idx >> 4) * SST + (idx & 15)] = Ssrc[idx];
    __syncthreads();

    #pragma unroll
    for (int pi = 0; pi < 4; ++pi) {
        int p = w * 4 + pi;
        float s0 = S[l * SST + p];
        float s1 = S[(64 + l) * SST + p];
        float s2 = (l + 128 < K_) ? S[(128 + l) * SST + p] : -1e30f;
        float m = fmaxf(fmaxf(s0, s1), s2);
        #pragma unroll
        for (int off = 32; off; off >>= 1) m = fmaxf(m, __shfl_xor(m, off));
        float e0 = __expf(s0 - m), e1 = __expf(s1 - m), e2 = __expf(s2 - m);
        float sum = e0 + e1 + e2;
        #pragma unroll
        for (int off = 32; off; off >>= 1) sum += __shfl_xor(sum, off);
        float inv = 1.0f / sum;
        S[l * SST + p] = e0 * inv;
        S[(64 + l) * SST + p] = e1 * inv;
        if (l + 128 < K_) S[(128 + l) * SST + p] = e2 * inv;
    }
    __syncthreads();

    int hl = w * 16 + lc;
    int hB = hh * 64 + hl;
    const ush* gBase = g + (size_t)(b * HC_ + hB) * DC_ * H_ * GW + x0 + grp * 8;
    bf16x8 bgb[2][7];
    #pragma unroll
    for (int i = 0; i < 7; ++i) {
        int ry = min(max(y0 + i - 3, 0), H_ - 1);
        bgb[0][i] = *(const bf16x8*)(gBase + (size_t)ry * GW);
    }
    f32x4 acc = {0.f, 0.f, 0.f, 0.f};
    #pragma unroll
    for (int d = 0; d < 3; ++d) {
        if (d < 2) {
            #pragma unroll
            for (int i = 0; i < 7; ++i) {
                int ry = min(max(y0 + i - 3, 0), H_ - 1);
                bgb[(d + 1) & 1][i] = *(const bf16x8*)(gBase + (size_t)((d + 1) * H_ + ry) * GW);
            }
        }
        #pragma unroll
        for (int i = 0; i < 7; ++i) {
            int idx = d * 7 + i;
            unsigned au[4];
            #pragma unroll
            for (int rr = 0; rr < 4; ++rr) {
                int k0 = grp * 8 + rr * 2;
                int j0 = k0 - lc, j1 = k0 + 1 - lc;
                float v0 = (j0 >= 0 && j0 < 7) ? S[(idx * 7 + j0) * SST + lc] : 0.f;
                float v1 = (j1 >= 0 && j1 < 7) ? S[(idx * 7 + j1) * SST + lc] : 0.f;
                au[rr] = (unsigned)f2bf(v0) | ((unsigned)f2bf(v1) << 16);
            }
            union { unsigned u[4]; bf16x8 v; } af;
            af.u[0] = au[0]; af.u[1] = au[1]; af.u[2] = au[2]; af.u[3] = au[3];
            acc = __builtin_amdgcn_mfma_f32_16x16x32_bf16(af.v, bgb[d & 1][i], acc, 0, 0, 0);
        }
    }
    #pragma unroll
    for (int r = 0; r < 4; ++r) {
        int p = grp * 4 + r;
        float v = acc[r];
        ush hv = f2bf(v);
        YS[0][p][hl] = hv;
        YS[1][p][hl] = f2bf(v - bf2f(hv));
    }
    __syncthreads();

    {
        int plane = t >> 7, r2 = t & 127;
        int px = r2 >> 3, ch = r2 & 7;
        ush8x v;
        #pragma unroll
        for (int i = 0; i < 8; ++i) v[i] = YS[plane][px][ch * 8 + i];
        ush* dst = (plane ? yL : yH) + (size_t)(pixBase + px) * HC_ + hh * 64 + ch * 8;
        *(ush8x*)dst = v;
    }
}

// ---------------------------------------------------------------------------
// 2c) wy GEMM (unchanged): DMA-staged, M=256, K=128, N=4608, grid 288.
__global__ __launch_bounds__(256) void wy_gemm_kernel(
    const ush* __restrict__ WwH, const ush* __restrict__ WwL,
    const ush* __restrict__ yHp, const ush* __restrict__ yLp,
    float* __restrict__ wyO)
{
    __shared__ __align__(16) unsigned char LB[32768];

    int bid = blockIdx.x;
    int swz = (bid & 7) * 36 + (bid >> 3);
    int otg = swz & 3, pxt = swz >> 2;
    int pxBase = pxt * 64;
    int b = pxBase / HW_;
    int pBase = pxBase - b * HW_;

    int t = threadIdx.x, w = t >> 6, l = t & 63, lc = l & 15, grp = l >> 4;
    const ush* GSRC = (w == 0) ? WwH : (w == 1) ? WwL : (w == 2) ? yHp : yLp;
    int rowBase = (w < 2) ? (otg * 64) : pxBase;
    int r8 = l >> 3;
    int kg = (l & 7) ^ r8;
    unsigned char* ldsPlane = LB + w * 8192;

    f32x4 acc0 = {0,0,0,0}, acc1 = {0,0,0,0}, acc2 = {0,0,0,0}, acc3 = {0,0,0,0};

    for (int kst = 0; kst < 2; ++kst) {
        __syncthreads();
        #pragma unroll
        for (int wl = 0; wl < 8; ++wl) {
            int row = rowBase + wl * 8 + r8;
            gload16(GSRC + (size_t)row * 128 + kst * 64 + kg * 8,
                    ldsPlane + wl * 1024);
        }
        __syncthreads();

        #pragma unroll
        for (int ksub = 0; ksub < 2; ++ksub) {
            int sw = ((ksub * 4 + grp) ^ (lc & 7)) << 4;
            int brow = w * 16 + lc;
            bf16x8 bh = *(const bf16x8*)(LB + 16384 + brow * 128 + sw);
            bf16x8 bl = *(const bf16x8*)(LB + 24576 + brow * 128 + sw);
            #pragma unroll
            for (int ot = 0; ot < 4; ++ot) {
                int arow = ot * 16 + lc;
                bf16x8 ah = *(const bf16x8*)(LB +        arow * 128 + sw);
                bf16x8 al = *(const bf16x8*)(LB + 8192 + arow * 128 + sw);
                f32x4 a = (ot == 0) ? acc0 : (ot == 1) ? acc1 : (ot == 2) ? acc2 : acc3;
                a = __builtin_amdgcn_mfma_f32_16x16x32_bf16(ah, bh, a, 0, 0, 0);
                a = __builtin_amdgcn_mfma_f32_16x16x32_bf16(ah, bl, a, 0, 0, 0);
                a = __builtin_amdgcn_mfma_f32_16x16x32_bf16(al, bh, a, 0, 0, 0);
                if (ot == 0) acc0 = a; else if (ot == 1) acc1 = a;
                else if (ot == 2) acc2 = a; else acc3 = a;
            }
        }
    }

    int p = pBase + w * 16 + lc;
    #pragma unroll
    for (int ot = 0; ot < 4; ++ot) {
        f32x4 a = (ot == 0) ? acc0 : (ot == 1) ? acc1 : (ot == 2) ? acc2 : acc3;
        int o0 = otg * 64 + ot * 16 + grp * 4;
        #pragma unroll
        for (int r = 0; r < 4; ++r)
            wyO[(size_t)(b * C_ + o0 + r) * HW_ + p] = a[r];
    }
}

// ---------------------------------------------------------------------------
// 3) FUSED BN stats + normalize + residual. grid 256 (one block per channel):
//    pass1 reduce wy[c]; pass2 apply (wy[c] L2-hot from pass1).
__global__ __launch_bounds__(256) void bnfinal_kernel(
    const float* __restrict__ wy, const float* __restrict__ x,
    const float* __restrict__ gamma, const float* __restrict__ beta,
    float* __restrict__ out)
{
    int o = blockIdx.x;
    int t = threadIdx.x;
    float s = 0.f, s2 = 0.f;
    for (int idx = t; idx < NP_; idx += 256) {
        int b = idx >= HW_;
        int p = idx - b * HW_;
        float v = wy[(size_t)(b * C_ + o) * HW_ + p];
        s += v;
        s2 = fmaf(v, v, s2);
    }
    #pragma unroll
    for (int off = 32; off; off >>= 1) {
        s  += __shfl_xor(s, off);
        s2 += __shfl_xor(s2, off);
    }
    __shared__ float ls[4], ls2[4];
    __shared__ float scS, shS;
    int wv = t >> 6, lane = t & 63;
    if (lane == 0) { ls[wv] = s; ls2[wv] = s2; }
    __syncthreads();
    if (t == 0) {
        float S  = ls[0] + ls[1] + ls[2] + ls[3];
        float S2 = ls2[0] + ls2[1] + ls2[2] + ls2[3];
        float mean = S / (float)NP_;
        float var = fmaxf(S2 / (float)NP_ - mean * mean, 0.f);
        float rstd = rsqrtf(var + 1e-5f);
        float sc = gamma[o] * rstd;
        scS = sc;
        shS = beta[o] - mean * sc;
    }
    __syncthreads();
    float sc = scS, sh = shS;
    for (int idx = t; idx < NP_ / 4; idx += 256) {
        int b = idx >= (HW_ / 4);
        int p4 = (idx - b * (HW_ / 4)) * 4;
        size_t e = (size_t)(b * C_ + o) * HW_ + p4;
        float4 wv = *(const float4*)(wy + e);
        float4 xv = *(const float4*)(x + e);
        float4 ov;
        ov.x = fmaf(wv.x, sc, xv.x + sh);
        ov.y = fmaf(wv.y, sc, xv.y + sh);
        ov.z = fmaf(wv.z, sc, xv.z + sh);
        ov.w = fmaf(wv.w, sc, xv.w + sh);
        *(float4*)(out + e) = ov;
    }
}

extern "C" void kernel_launch(void* const* d_in, const int* in_sizes, int n_in,
                              void* d_out, int out_size, void* d_ws, size_t ws_size,
                              hipStream_t stream) {
    const float* x       = (const float*)d_in[0];
    const float* ctx     = (const float*)d_in[1];
    const float* theta_w = (const float*)d_in[2];
    const float* psi_w   = (const float*)d_in[3];
    const float* g_w     = (const float*)d_in[4];
    const float* W_w     = (const float*)d_in[5];
    // d_in[6] = W_b: unused, cancels exactly under training-mode BN
    const float* gamma   = (const float*)d_in[7];
    const float* beta    = (const float*)d_in[8];
    float* out = (float*)d_out;

    ush* ws = (ush*)d_ws;
    ush* qH    = ws;                     // 589824
    ush* qL    = qH + 589824;
    ush* psiH  = qL + 589824;            // 1769472
    ush* psiL  = psiH + 1769472;
    ush* gB    = psiL + 1769472;         // 2359296  [B,128,3,48,64] padded
    ush* gtmp  = gB + 2359296;           // 3538944  [B,128,3,48,48] unpadded
    ush* WpgH  = gtmp + 3538944;         // 65536
    ush* WpgL  = WpgH + 65536;
    ush* WqH   = WpgL + 65536;           // 32768
    ush* WqL   = WqH + 32768;
    ush* WwH   = WqL + 32768;            // 32768
    ush* WwL   = WwH + 32768;
    ush* ctxTH = WwL + 32768;            // 3538944
    ush* ctxTL = ctxTH + 3538944;
    ush* xTH   = ctxTL + 3538944;        // 1179648
    ush* xTL   = xTH + 1179648;
    // aliases (stream-ordered single-call lifetimes, deterministic each call):
    float* wyB = (float*)ctxTH;          // wy f32 <= ctxT region (dead after proj4)
    float* Sg  = (float*)gtmp;           // scores 2.71MB <= gtmp (dead after pad2)
    ush* yH = xTH;                       // y planes <= xT region (dead after proj4)
    ush* yL = xTH + 589824;

    prep_kernel<<<dim3(1280), 256, 0, stream>>>(ctx, x, psi_w, g_w, theta_w, W_w,
                                                ctxTH, ctxTL, xTH, xTL,
                                                WpgH, WpgL, WqH, WqL, WwH, WwL);
    proj4_kernel<<<dim3(1008), 256, 0, stream>>>(WpgH, WpgL, WqH, WqL,
                                                 ctxTH, ctxTL, xTH, xTL,
                                                 psiH, psiL, gtmp, qH, qL);
    pad2_kernel<<<dim3(1152), 256, 0, stream>>>(gtmp, gB);
    scores2_kernel<<<dim3(864), 256, 0, stream>>>(qH, qL, psiH, psiL, Sg);
    smpv_kernel<<<dim3(576), 256, 0, stream>>>(Sg, gB, yH, yL);
    wy_gemm_kernel<<<dim3(288), 256, 0, stream>>>(WwH, WwL, yH, yL, wyB);
    bnfinal_kernel<<<dim3(C_), 256, 0, stream>>>(wyB, x, gamma, beta, out);
}

// Round 17
// 67.024 us; speedup vs baseline: 1.1619x; 1.0334x over previous
//
#include <hip/hip_runtime.h>
#include <cmath>

#define B_   2
#define C_   256
#define HC_  128
#define DC_  3
#define H_   48
#define W_   48
#define HW_  (H_ * W_)      // 2304
#define NP_  (B_ * HW_)     // 4608
#define K_   (DC_ * 49)     // 147
#define GW   64             // padded g width (col = x+3, 16B-aligned rows)
#define SST  19             // S stride (words) in smpv

typedef unsigned short ush;
typedef __attribute__((ext_vector_type(8))) short bf16x8;
typedef __attribute__((ext_vector_type(8))) unsigned short ush8x;
typedef __attribute__((ext_vector_type(4))) float f32x4;
typedef __attribute__((ext_vector_type(4))) unsigned u32x4;

__device__ inline ush f2bf(float f) {
    union { float f; unsigned u; } v; v.f = f;
    unsigned r = v.u + 0x7FFF + ((v.u >> 16) & 1);
    return (ush)(r >> 16);
}
__device__ inline float bf2f(ush h) {
    union { unsigned u; float f; } v; v.u = ((unsigned)h) << 16;
    return v.f;
}
__device__ inline unsigned packhl(float f) {
    ush h = f2bf(f);
    ush l = f2bf(f - bf2f(h));
    return (unsigned)h | ((unsigned)l << 16);
}
__device__ __forceinline__ void gload16(const void* g, void* l) {
    __builtin_amdgcn_global_load_lds(
        (const __attribute__((address_space(1))) unsigned*)g,
        (__attribute__((address_space(3))) unsigned*)l, 16, 0, 0);
}

// ---------------------------------------------------------------------------
// 0) prep: transpose+split ctx/x; weight hi/lo split. (unchanged)
__global__ __launch_bounds__(256) void prep_kernel(
    const float* __restrict__ ctx, const float* __restrict__ x,
    const float* __restrict__ psi_w, const float* __restrict__ g_w,
    const float* __restrict__ theta_w, const float* __restrict__ Ww,
    ush* __restrict__ ctxTH, ush* __restrict__ ctxTL,
    ush* __restrict__ xTH, ush* __restrict__ xTL,
    ush* __restrict__ WpgH, ush* __restrict__ WpgL,
    ush* __restrict__ WqH, ush* __restrict__ WqL,
    ush* __restrict__ WwH, ush* __restrict__ WwL)
{
    __shared__ float T[64][65];
    int id = blockIdx.x;
    if (id >= 1152) {
        int idx = ((id - 1152) * 256 + threadIdx.x) * 4;
        float4 v;
        ush *dH, *dL;
        if (idx < 65536) {
            v = *(const float4*)(idx < 32768 ? psi_w + idx : g_w + (idx - 32768));
            dH = WpgH + idx; dL = WpgL + idx;
        } else if (idx < 98304) {
            v = *(const float4*)(theta_w + idx - 65536);
            dH = WqH + idx - 65536; dL = WqL + idx - 65536;
        } else {
            v = *(const float4*)(Ww + idx - 98304);
            dH = WwH + idx - 98304; dL = WwL + idx - 98304;
        }
        ushort4 h, l;
        h.x = f2bf(v.x); l.x = f2bf(v.x - bf2f(h.x));
        h.y = f2bf(v.y); l.y = f2bf(v.y - bf2f(h.y));
        h.z = f2bf(v.z); l.z = f2bf(v.z - bf2f(h.z));
        h.w = f2bf(v.w); l.w = f2bf(v.w - bf2f(h.w));
        *(ushort4*)dH = h; *(ushort4*)dL = l;
        return;
    }
    const float* src;
    ush *dH, *dL;
    size_t rowStride;
    if (id < 864) {
        int ct = id & 3, pt = (id >> 2) % 36, bd = id / 144;
        int b = bd / 3, d = bd % 3;
        int c0 = ct * 64, p0 = pt * 64;
        src = ctx + ((size_t)(b * 256 + c0) * 3 + d) * HW_ + p0;
        rowStride = 3 * HW_;
        size_t ob = ((size_t)(b * 3 + d) * HW_ + p0) * 256 + c0;
        dH = ctxTH + ob; dL = ctxTL + ob;
    } else {
        int id2 = id - 864;
        int ct = id2 & 3, pt = (id2 >> 2) % 36, b = id2 / 144;
        int c0 = ct * 64, p0 = pt * 64;
        src = x + (size_t)(b * 256 + c0) * HW_ + p0;
        rowStride = HW_;
        size_t ob = ((size_t)b * HW_ + p0) * 256 + c0;
        dH = xTH + ob; dL = xTL + ob;
    }
    int t = threadIdx.x;
    int cl = t >> 4, p4 = (t & 15) * 4;
    #pragma unroll
    for (int r = 0; r < 4; ++r) {
        int c = cl + r * 16;
        float4 v = *(const float4*)(src + (size_t)c * rowStride + p4);
        T[c][p4] = v.x; T[c][p4 + 1] = v.y; T[c][p4 + 2] = v.z; T[c][p4 + 3] = v.w;
    }
    __syncthreads();
    int pl = t >> 2, ch = t & 3;
    #pragma unroll
    for (int s = 0; s < 2; ++s) {
        int c8 = (ch + s * 4) * 8;
        ush8x vh, vl;
        #pragma unroll
        for (int i = 0; i < 8; ++i) {
            float f = T[c8 + i][pl];
            ush hh = f2bf(f);
            vh[i] = hh;
            vl[i] = f2bf(f - bf2f(hh));
        }
        *(ush8x*)(dH + (size_t)pl * 256 + c8) = vh;
        *(ush8x*)(dL + (size_t)pl * 256 + c8) = vl;
    }
}

// ---------------------------------------------------------------------------
// 1) proj4 (unchanged)
__global__ __launch_bounds__(256) void proj4_kernel(
    const ush* __restrict__ WpgH, const ush* __restrict__ WpgL,
    const ush* __restrict__ WqH, const ush* __restrict__ WqL,
    const ush* __restrict__ ctxTH, const ush* __restrict__ ctxTL,
    const ush* __restrict__ xTH, const ush* __restrict__ xTL,
    ush* __restrict__ psiH, ush* __restrict__ psiL,
    ush* __restrict__ gtmp, ush* __restrict__ qH, ush* __restrict__ qL)
{
    __shared__ __align__(16) unsigned char LB[32768];

    int bid = blockIdx.x;
    int swz = (bid & 7) * 126 + (bid >> 3);
    int t = threadIdx.x, w = t >> 6, l = t & 63, lc = l & 15, grp = l >> 4;
    int mode, b, d, pxBase, otg;
    const ush *XH, *XL, *WH, *WL;
    if (swz < 864) {
        mode = 0; otg = swz & 3;
        int rest = swz >> 2;
        int pxt = rest % 36, bd = rest / 36;
        b = bd / 3; d = bd % 3;
        pxBase = pxt * 64;
        size_t xb = (size_t)(b * 3 + d) * HW_ * 256;
        XH = ctxTH + xb; XL = ctxTL + xb;
        WH = WpgH; WL = WpgL;
    } else {
        mode = 1;
        int id2 = swz - 864; otg = id2 & 1;
        int rest = id2 >> 1;
        int pxt = rest % 36; b = rest / 36; d = 0;
        pxBase = pxt * 64;
        size_t xb = (size_t)b * HW_ * 256;
        XH = xTH + xb; XL = xTL + xb;
        WH = WqH; WL = WqL;
    }

    const ush* GSRC = (w == 0) ? WH : (w == 1) ? WL : (w == 2) ? XH : XL;
    int rowBase = (w < 2) ? (otg * 64) : pxBase;
    int r8 = l >> 3;
    int kg = (l & 7) ^ r8;
    unsigned char* ldsPlane = LB + w * 8192;

    f32x4 acc0 = {0,0,0,0}, acc1 = {0,0,0,0}, acc2 = {0,0,0,0}, acc3 = {0,0,0,0};

    for (int kst = 0; kst < 4; ++kst) {
        __syncthreads();
        #pragma unroll
        for (int wl = 0; wl < 8; ++wl) {
            int row = rowBase + wl * 8 + r8;
            gload16(GSRC + (size_t)row * 256 + kst * 64 + kg * 8,
                    ldsPlane + wl * 1024);
        }
        __syncthreads();

        #pragma unroll
        for (int ksub = 0; ksub < 2; ++ksub) {
            int sw = ((ksub * 4 + grp) ^ (lc & 7)) << 4;
            int brow = w * 16 + lc;
            bf16x8 bh = *(const bf16x8*)(LB + 16384 + brow * 128 + sw);
            bf16x8 bl = *(const bf16x8*)(LB + 24576 + brow * 128 + sw);
            #pragma unroll
            for (int ot = 0; ot < 4; ++ot) {
                int arow = ot * 16 + lc;
                bf16x8 ah = *(const bf16x8*)(LB +        arow * 128 + sw);
                bf16x8 al = *(const bf16x8*)(LB + 8192 + arow * 128 + sw);
                f32x4 a = (ot == 0) ? acc0 : (ot == 1) ? acc1 : (ot == 2) ? acc2 : acc3;
                a = __builtin_amdgcn_mfma_f32_16x16x32_bf16(ah, bh, a, 0, 0, 0);
                a = __builtin_amdgcn_mfma_f32_16x16x32_bf16(ah, bl, a, 0, 0, 0);
                a = __builtin_amdgcn_mfma_f32_16x16x32_bf16(al, bh, a, 0, 0, 0);
                if (ot == 0) acc0 = a; else if (ot == 1) acc1 = a;
                else if (ot == 2) acc2 = a; else acc3 = a;
            }
        }
    }

    __syncthreads();
    unsigned (*T)[68] = (unsigned(*)[68])LB;
    {
        u32x4 pv;
        pv[0] = packhl(acc0[0]); pv[1] = packhl(acc0[1]);
        pv[2] = packhl(acc0[2]); pv[3] = packhl(acc0[3]);
        *(u32x4*)&T[w * 16 + lc][0 * 16 + grp * 4] = pv;
        pv[0] = packhl(acc1[0]); pv[1] = packhl(acc1[1]);
        pv[2] = packhl(acc1[2]); pv[3] = packhl(acc1[3]);
        *(u32x4*)&T[w * 16 + lc][1 * 16 + grp * 4] = pv;
        pv[0] = packhl(acc2[0]); pv[1] = packhl(acc2[1]);
        pv[2] = packhl(acc2[2]); pv[3] = packhl(acc2[3]);
        *(u32x4*)&T[w * 16 + lc][2 * 16 + grp * 4] = pv;
        pv[0] = packhl(acc3[0]); pv[1] = packhl(acc3[1]);
        pv[2] = packhl(acc3[2]); pv[3] = packhl(acc3[3]);
        *(u32x4*)&T[w * 16 + lc][3 * 16 + grp * 4] = pv;
    }
    __syncthreads();

    if (mode == 1 || otg < 2) {
        ush* PH = (mode == 0) ? psiH : qH;
        ush* PL = (mode == 0) ? psiL : qL;
        #pragma unroll
        for (int it = 0; it < 2; ++it) {
            int idx = it * 256 + t;
            int pxl = idx >> 3, ch = idx & 7;
            u32x4 v0 = *(const u32x4*)&T[pxl][ch * 8];
            u32x4 v1 = *(const u32x4*)&T[pxl][ch * 8 + 4];
            ush8x hi, lo;
            #pragma unroll
            for (int i = 0; i < 4; ++i) {
                hi[i] = (ush)(v0[i] & 0xffffu); lo[i] = (ush)(v0[i] >> 16);
                hi[4 + i] = (ush)(v1[i] & 0xffffu); lo[4 + i] = (ush)(v1[i] >> 16);
            }
            int pix = pxBase + pxl;
            size_t base;
            if (mode == 0)
                base = ((size_t)(b * DC_ + d) * HW_ + pix) * HC_ + otg * 64 + ch * 8;
            else
                base = ((size_t)b * HW_ + pix) * HC_ + otg * 64 + ch * 8;
            *(ush8x*)&PH[base] = hi;
            *(ush8x*)&PL[base] = lo;
        }
    } else {
        #pragma unroll
        for (int it = 0; it < 2; ++it) {
            int idx = it * 256 + t;
            int ol = idx >> 3, pg = idx & 7;
            ush8x hv;
            #pragma unroll
            for (int i = 0; i < 8; ++i)
                hv[i] = (ush)(T[pg * 8 + i][ol] & 0xffffu);
            int og = (otg - 2) * 64 + ol;
            int pxg = pxBase + pg * 8;
            int yy = pxg / W_, xx = pxg - yy * W_;
            *(ush8x*)&gtmp[(((size_t)(b * HC_ + og) * DC_ + d) * H_ + yy) * W_ + xx] = hv;
        }
    }
}

// ---------------------------------------------------------------------------
// 1b) pad (unchanged)
__global__ __launch_bounds__(256) void pad2_kernel(
    const ush* __restrict__ gtmp, ush* __restrict__ gB)
{
    __shared__ ush R[32][48];
    int blk = blockIdx.x, t = threadIdx.x;
    int r = t >> 3, ch = t & 7;
    size_t row = (size_t)blk * 32 + r;
    if (ch < 6)
        *(ush8x*)&R[r][ch * 8] = *(const ush8x*)&gtmp[row * W_ + ch * 8];
    __syncthreads();
    ush8x o;
    #pragma unroll
    for (int i = 0; i < 8; ++i) {
        int x = ch * 8 + i - 3;
        x = min(max(x, 0), W_ - 1);
        o[i] = R[r][x];
    }
    *(ush8x*)&gB[row * GW + ch * 8] = o;
}

// ---------------------------------------------------------------------------
// 2a) scores2 (unchanged): DMA-staged psi/q, pipelined over window rows.
__global__ __launch_bounds__(256) void scores2_kernel(
    const ush* __restrict__ qHp, const ush* __restrict__ qLp,
    const ush* __restrict__ psiHp, const ush* __restrict__ psiLp,
    float* __restrict__ Sg)
{
    __shared__ __align__(16) unsigned char QS[8192];
    __shared__ __align__(16) unsigned char PB[2][16384];
    __shared__ float SP[2][49 * 16];

    int bid = blockIdx.x;
    int swz = (bid & 7) * 108 + (bid >> 3);
    int tile = swz / 3, d = swz - 3 * tile;
    int b = tile / 144;
    int tr = tile - b * 144;
    int y0 = tr / 3;
    int x0 = (tr % 3) * 16;

    int t = threadIdx.x;
    int w = t >> 6, l = t & 63, lc = l & 15, grp = l >> 4;
    int pixBase = b * HW_ + y0 * W_ + x0;
    size_t dOff = (size_t)(b * DC_ + d) * HW_ * HC_;

    #pragma unroll
    for (int jj = 0; jj < 2; ++jj) {
        int s = jj * 256 + t;
        int plane = s >> 8, rest = s & 255;
        int px = rest >> 4, sl = rest & 15;
        const ush* SRC = plane ? qLp : qHp;
        gload16(SRC + (size_t)(pixBase + px) * HC_ + ((sl ^ (px & 7)) * 8),
                QS + s * 16);
    }

    auto stageP = [&](int i, int buf) {
        int ry = min(max(y0 + i - 3, 0), H_ - 1);
        size_t rowOff = dOff + (size_t)ry * W_ * HC_;
        #pragma unroll
        for (int jj = 0; jj < 4; ++jj) {
            int s = jj * 256 + t;
            int plane = s >> 9, rest = s & 511;
            int pxp = rest >> 4, sl = rest & 15;
            int px = min(max(x0 + pxp - 3, 0), W_ - 1);
            const ush* SRC = plane ? psiLp : psiHp;
            gload16(SRC + rowOff + (size_t)px * HC_ + ((sl ^ (pxp & 7)) * 8),
                    PB[buf] + s * 16);
        }
    };

    stageP(0, 0);
    __syncthreads();

    int f = w & 1, kh = w >> 1;
    int c = f * 16 + lc;
    bf16x8 qh[2], ql[2];
    #pragma unroll
    for (int k2 = 0; k2 < 2; ++k2) {
        int K = (kh * 2 + k2) * 4 + grp;
        int s = K ^ (lc & 7);
        qh[k2] = *(const bf16x8*)(QS + (lc * 16 + s) * 16);
        ql[k2] = *(const bf16x8*)(QS + 4096 + (lc * 16 + s) * 16);
    }

    for (int i = 0; i < 7; ++i) {
        if (i < 6) stageP(i + 1, (i + 1) & 1);
        const unsigned char* CB = PB[i & 1];
        f32x4 acc = {0.f, 0.f, 0.f, 0.f};
        #pragma unroll
        for (int k2 = 0; k2 < 2; ++k2) {
            int K = (kh * 2 + k2) * 4 + grp;
            int s = K ^ (c & 7);
            bf16x8 ph = *(const bf16x8*)(CB + (c * 16 + s) * 16);
            bf16x8 pl = *(const bf16x8*)(CB + 8192 + (c * 16 + s) * 16);
            acc = __builtin_amdgcn_mfma_f32_16x16x32_bf16(qh[k2], ph, acc, 0, 0, 0);
            acc = __builtin_amdgcn_mfma_f32_16x16x32_bf16(qh[k2], pl, acc, 0, 0, 0);
            acc = __builtin_amdgcn_mfma_f32_16x16x32_bf16(ql[k2], ph, acc, 0, 0, 0);
        }
        #pragma unroll
        for (int r = 0; r < 4; ++r) {
            int pp = grp * 4 + r;
            int j2 = c - pp;
            if (j2 >= 0 && j2 < 7) SP[kh][(i * 7 + j2) * 16 + pp] = acc[r];
        }
        __syncthreads();
    }

    float* dst = Sg + ((size_t)tile * 3 + d) * 784;
    for (int idx = t; idx < 784; idx += 256)
        dst[idx] = SP[0][idx] + SP[1][idx];
}

// ---------------------------------------------------------------------------
// 2b) smpv (unchanged)
__global__ __launch_bounds__(256) void smpv_kernel(
    const float* __restrict__ Sg, const ush* __restrict__ g,
    ush* __restrict__ yH, ush* __restrict__ yL)
{
    __shared__ float S[147 * SST];
    __shared__ ush YS[2][16][72];

    int bid = blockIdx.x;
    int swz = (bid & 7) * 72 + (bid >> 3);
    int tile = swz >> 1, hh = swz & 1;
    int b = tile / 144;
    int tr = tile - b * 144;
    int y0 = tr / 3;
    int x0 = (tr % 3) * 16;

    int t = threadIdx.x;
    int w = t >> 6, l = t & 63, lc = l & 15, grp = l >> 4;
    int pixBase = b * HW_ + y0 * W_ + x0;

    const float* Ssrc = Sg + (size_t)tile * 2352;
    for (int idx = t; idx < 2352; idx += 256)
        S[(idx >> 4) * SST + (idx & 15)] = Ssrc[idx];
    __syncthreads();

    #pragma unroll
    for (int pi = 0; pi < 4; ++pi) {
        int p = w * 4 + pi;
        float s0 = S[l * SST + p];
        float s1 = S[(64 + l) * SST + p];
        float s2 = (l + 128 < K_) ? S[(128 + l) * SST + p] : -1e30f;
        float m = fmaxf(fmaxf(s0, s1), s2);
        #pragma unroll
        for (int off = 32; off; off >>= 1) m = fmaxf(m, __shfl_xor(m, off));
        float e0 = __expf(s0 - m), e1 = __expf(s1 - m), e2 = __expf(s2 - m);
        float sum = e0 + e1 + e2;
        #pragma unroll
        for (int off = 32; off; off >>= 1) sum += __shfl_xor(sum, off);
        float inv = 1.0f / sum;
        S[l * SST + p] = e0 * inv;
        S[(64 + l) * SST + p] = e1 * inv;
        if (l + 128 < K_) S[(128 + l) * SST + p] = e2 * inv;
    }
    __syncthreads();

    int hl = w * 16 + lc;
    int hB = hh * 64 + hl;
    const ush* gBase = g + (size_t)(b * HC_ + hB) * DC_ * H_ * GW + x0 + grp * 8;
    bf16x8 bgb[2][7];
    #pragma unroll
    for (int i = 0; i < 7; ++i) {
        int ry = min(max(y0 + i - 3, 0), H_ - 1);
        bgb[0][i] = *(const bf16x8*)(gBase + (size_t)ry * GW);
    }
    f32x4 acc = {0.f, 0.f, 0.f, 0.f};
    #pragma unroll
    for (int d = 0; d < 3; ++d) {
        if (d < 2) {
            #pragma unroll
            for (int i = 0; i < 7; ++i) {
                int ry = min(max(y0 + i - 3, 0), H_ - 1);
                bgb[(d + 1) & 1][i] = *(const bf16x8*)(gBase + (size_t)((d + 1) * H_ + ry) * GW);
            }
        }
        #pragma unroll
        for (int i = 0; i < 7; ++i) {
            int idx = d * 7 + i;
            unsigned au[4];
            #pragma unroll
            for (int rr = 0; rr < 4; ++rr) {
                int k0 = grp * 8 + rr * 2;
                int j0 = k0 - lc, j1 = k0 + 1 - lc;
                float v0 = (j0 >= 0 && j0 < 7) ? S[(idx * 7 + j0) * SST + lc] : 0.f;
                float v1 = (j1 >= 0 && j1 < 7) ? S[(idx * 7 + j1) * SST + lc] : 0.f;
                au[rr] = (unsigned)f2bf(v0) | ((unsigned)f2bf(v1) << 16);
            }
            union { unsigned u[4]; bf16x8 v; } af;
            af.u[0] = au[0]; af.u[1] = au[1]; af.u[2] = au[2]; af.u[3] = au[3];
            acc = __builtin_amdgcn_mfma_f32_16x16x32_bf16(af.v, bgb[d & 1][i], acc, 0, 0, 0);
        }
    }
    #pragma unroll
    for (int r = 0; r < 4; ++r) {
        int p = grp * 4 + r;
        float v = acc[r];
        ush hv = f2bf(v);
        YS[0][p][hl] = hv;
        YS[1][p][hl] = f2bf(v - bf2f(hv));
    }
    __syncthreads();

    {
        int plane = t >> 7, r2 = t & 127;
        int px = r2 >> 3, ch = r2 & 7;
        ush8x v;
        #pragma unroll
        for (int i = 0; i < 8; ++i) v[i] = YS[plane][px][ch * 8 + i];
        ush* dst = (plane ? yL : yH) + (size_t)(pixBase + px) * HC_ + hh * 64 + ch * 8;
        *(ush8x*)dst = v;
    }
}

// ---------------------------------------------------------------------------
// 2c) wy GEMM v2: DMA-staged; NEW epilogue writes wy as bf16 (coalesced via
//     LDS transpose) + per-block per-channel partial (sum, sumsq) for BN.
__global__ __launch_bounds__(256) void wy_gemm2_kernel(
    const ush* __restrict__ WwH, const ush* __restrict__ WwL,
    const ush* __restrict__ yHp, const ush* __restrict__ yLp,
    ush* __restrict__ wyO, float2* __restrict__ partials)
{
    __shared__ __align__(16) unsigned char LB[32768];
    __shared__ ush T2[64][76];
    __shared__ float partS[4][64], partQ[4][64];

    int bid = blockIdx.x;
    int swz = (bid & 7) * 36 + (bid >> 3);    // 288 = 8*36
    int otg = swz & 3, pxt = swz >> 2;
    int pxBase = pxt * 64;
    int b = pxBase / HW_;
    int pBase = pxBase - b * HW_;

    int t = threadIdx.x, w = t >> 6, l = t & 63, lc = l & 15, grp = l >> 4;
    const ush* GSRC = (w == 0) ? WwH : (w == 1) ? WwL : (w == 2) ? yHp : yLp;
    int rowBase = (w < 2) ? (otg * 64) : pxBase;
    int r8 = l >> 3;
    int kg = (l & 7) ^ r8;
    unsigned char* ldsPlane = LB + w * 8192;

    f32x4 acc0 = {0,0,0,0}, acc1 = {0,0,0,0}, acc2 = {0,0,0,0}, acc3 = {0,0,0,0};

    for (int kst = 0; kst < 2; ++kst) {
        __syncthreads();
        #pragma unroll
        for (int wl = 0; wl < 8; ++wl) {
            int row = rowBase + wl * 8 + r8;
            gload16(GSRC + (size_t)row * 128 + kst * 64 + kg * 8,
                    ldsPlane + wl * 1024);
        }
        __syncthreads();

        #pragma unroll
        for (int ksub = 0; ksub < 2; ++ksub) {
            int sw = ((ksub * 4 + grp) ^ (lc & 7)) << 4;
            int brow = w * 16 + lc;
            bf16x8 bh = *(const bf16x8*)(LB + 16384 + brow * 128 + sw);
            bf16x8 bl = *(const bf16x8*)(LB + 24576 + brow * 128 + sw);
            #pragma unroll
            for (int ot = 0; ot < 4; ++ot) {
                int arow = ot * 16 + lc;
                bf16x8 ah = *(const bf16x8*)(LB +        arow * 128 + sw);
                bf16x8 al = *(const bf16x8*)(LB + 8192 + arow * 128 + sw);
                f32x4 a = (ot == 0) ? acc0 : (ot == 1) ? acc1 : (ot == 2) ? acc2 : acc3;
                a = __builtin_amdgcn_mfma_f32_16x16x32_bf16(ah, bh, a, 0, 0, 0);
                a = __builtin_amdgcn_mfma_f32_16x16x32_bf16(ah, bl, a, 0, 0, 0);
                a = __builtin_amdgcn_mfma_f32_16x16x32_bf16(al, bh, a, 0, 0, 0);
                if (ot == 0) acc0 = a; else if (ot == 1) acc1 = a;
                else if (ot == 2) acc2 = a; else acc3 = a;
            }
        }
    }
    __syncthreads();

    // per-channel partial sums over this block's 64 px (shfl over lc group)
    float sv[16], qv[16];
    #pragma unroll
    for (int ot = 0; ot < 4; ++ot) {
        f32x4 a = (ot == 0) ? acc0 : (ot == 1) ? acc1 : (ot == 2) ? acc2 : acc3;
        #pragma unroll
        for (int r = 0; r < 4; ++r) {
            sv[ot * 4 + r] = a[r];
            qv[ot * 4 + r] = a[r] * a[r];
        }
    }
    #pragma unroll
    for (int m = 1; m < 16; m <<= 1) {
        #pragma unroll
        for (int i = 0; i < 16; ++i) {
            sv[i] += __shfl_xor(sv[i], m);
            qv[i] += __shfl_xor(qv[i], m);
        }
    }
    if (lc == 0) {
        #pragma unroll
        for (int ot = 0; ot < 4; ++ot)
            #pragma unroll
            for (int r = 0; r < 4; ++r) {
                partS[w][ot * 16 + grp * 4 + r] = sv[ot * 4 + r];
                partQ[w][ot * 16 + grp * 4 + r] = qv[ot * 4 + r];
            }
    }
    // bf16 values into LDS transpose buffer T2[o][px]
    #pragma unroll
    for (int ot = 0; ot < 4; ++ot) {
        f32x4 a = (ot == 0) ? acc0 : (ot == 1) ? acc1 : (ot == 2) ? acc2 : acc3;
        #pragma unroll
        for (int r = 0; r < 4; ++r)
            T2[ot * 16 + grp * 4 + r][w * 16 + lc] = f2bf(a[r]);
    }
    __syncthreads();

    // coalesced bf16 stores: 64 rows x 8 chunks of 8
    #pragma unroll
    for (int it = 0; it < 2; ++it) {
        int idx = it * 256 + t;
        int row = idx >> 3, ch = idx & 7;
        ushort4 v0 = *(const ushort4*)&T2[row][ch * 8];
        ushort4 v1 = *(const ushort4*)&T2[row][ch * 8 + 4];
        ush8x v;
        v[0] = v0.x; v[1] = v0.y; v[2] = v0.z; v[3] = v0.w;
        v[4] = v1.x; v[5] = v1.y; v[6] = v1.z; v[7] = v1.w;
        *(ush8x*)&wyO[(size_t)(b * C_ + otg * 64 + row) * HW_ + pBase + ch * 8] = v;
    }
    if (t < 64) {
        float s = partS[0][t] + partS[1][t] + partS[2][t] + partS[3][t];
        float q = partQ[0][t] + partQ[1][t] + partQ[2][t] + partQ[3][t];
        partials[(size_t)(otg * 64 + t) * 72 + pxt] = make_float2(s, q);
    }
}

// ---------------------------------------------------------------------------
// 3) bnfinal2: reduce 72 partials per channel + normalize + residual.
__global__ __launch_bounds__(256) void bnfinal2_kernel(
    const ush* __restrict__ wy, const float2* __restrict__ partials,
    const float* __restrict__ x,
    const float* __restrict__ gamma, const float* __restrict__ beta,
    float* __restrict__ out)
{
    int o = blockIdx.x;
    int t = threadIdx.x;
    float s = 0.f, q = 0.f;
    if (t < 72) {
        float2 v = partials[(size_t)o * 72 + t];
        s = v.x; q = v.y;
    }
    #pragma unroll
    for (int off = 32; off; off >>= 1) {
        s += __shfl_xor(s, off);
        q += __shfl_xor(q, off);
    }
    __shared__ float ls[4], lq[4];
    __shared__ float scS, shS;
    int wv = t >> 6, lane = t & 63;
    if (lane == 0) { ls[wv] = s; lq[wv] = q; }
    __syncthreads();
    if (t == 0) {
        float S = ls[0] + ls[1] + ls[2] + ls[3];
        float Q = lq[0] + lq[1] + lq[2] + lq[3];
        float mean = S / (float)NP_;
        float var = fmaxf(Q / (float)NP_ - mean * mean, 0.f);
        float rstd = rsqrtf(var + 1e-5f);
        float sc = gamma[o] * rstd;
        scS = sc;
        shS = beta[o] - mean * sc;
    }
    __syncthreads();
    float sc = scS, sh = shS;
    for (int idx = t; idx < NP_ / 8; idx += 256) {
        int b = idx >= (HW_ / 8);
        int p8 = (idx - b * (HW_ / 8)) * 8;
        size_t e = (size_t)(b * C_ + o) * HW_ + p8;
        ush8x w8 = *(const ush8x*)&wy[e];
        float4 x0 = *(const float4*)(x + e);
        float4 x1 = *(const float4*)(x + e + 4);
        float4 o0, o1;
        o0.x = fmaf(bf2f(w8[0]), sc, x0.x + sh);
        o0.y = fmaf(bf2f(w8[1]), sc, x0.y + sh);
        o0.z = fmaf(bf2f(w8[2]), sc, x0.z + sh);
        o0.w = fmaf(bf2f(w8[3]), sc, x0.w + sh);
        o1.x = fmaf(bf2f(w8[4]), sc, x1.x + sh);
        o1.y = fmaf(bf2f(w8[5]), sc, x1.y + sh);
        o1.z = fmaf(bf2f(w8[6]), sc, x1.z + sh);
        o1.w = fmaf(bf2f(w8[7]), sc, x1.w + sh);
        *(float4*)(out + e) = o0;
        *(float4*)(out + e + 4) = o1;
    }
}

extern "C" void kernel_launch(void* const* d_in, const int* in_sizes, int n_in,
                              void* d_out, int out_size, void* d_ws, size_t ws_size,
                              hipStream_t stream) {
    const float* x       = (const float*)d_in[0];
    const float* ctx     = (const float*)d_in[1];
    const float* theta_w = (const float*)d_in[2];
    const float* psi_w   = (const float*)d_in[3];
    const float* g_w     = (const float*)d_in[4];
    const float* W_w     = (const float*)d_in[5];
    // d_in[6] = W_b: unused, cancels exactly under training-mode BN
    const float* gamma   = (const float*)d_in[7];
    const float* beta    = (const float*)d_in[8];
    float* out = (float*)d_out;

    ush* ws = (ush*)d_ws;
    ush* qH    = ws;                     // 589824
    ush* qL    = qH + 589824;
    ush* psiH  = qL + 589824;            // 1769472
    ush* psiL  = psiH + 1769472;
    ush* gB    = psiL + 1769472;         // 2359296  [B,128,3,48,64] padded
    ush* gtmp  = gB + 2359296;           // 3538944  [B,128,3,48,48] unpadded
    ush* WpgH  = gtmp + 3538944;         // 65536
    ush* WpgL  = WpgH + 65536;
    ush* WqH   = WpgL + 65536;           // 32768
    ush* WqL   = WqH + 32768;
    ush* WwH   = WqL + 32768;            // 32768
    ush* WwL   = WwH + 32768;
    ush* ctxTH = WwL + 32768;            // 3538944
    ush* ctxTL = ctxTH + 3538944;
    ush* xTH   = ctxTL + 3538944;        // 1179648
    ush* xTL   = xTH + 1179648;
    float2* partials = (float2*)(xTL + 1179648);  // 256*72 float2 = 147456 B
    // aliases (stream-ordered single-call lifetimes, deterministic each call):
    ush* wyB  = ctxTH;                   // wy bf16 <= ctxT region (dead after proj4)
    float* Sg = (float*)gtmp;            // scores 2.71MB <= gtmp (dead after pad2)
    ush* yH = xTH;                       // y planes <= xT region (dead after proj4)
    ush* yL = xTH + 589824;

    prep_kernel<<<dim3(1280), 256, 0, stream>>>(ctx, x, psi_w, g_w, theta_w, W_w,
                                                ctxTH, ctxTL, xTH, xTL,
                                                WpgH, WpgL, WqH, WqL, WwH, WwL);
    proj4_kernel<<<dim3(1008), 256, 0, stream>>>(WpgH, WpgL, WqH, WqL,
                                                 ctxTH, ctxTL, xTH, xTL,
                                                 psiH, psiL, gtmp, qH, qL);
    pad2_kernel<<<dim3(1152), 256, 0, stream>>>(gtmp, gB);
    scores2_kernel<<<dim3(864), 256, 0, stream>>>(qH, qL, psiH, psiL, Sg);
    smpv_kernel<<<dim3(576), 256, 0, stream>>>(Sg, gB, yH, yL);
    wy_gemm2_kernel<<<dim3(288), 256, 0, stream>>>(WwH, WwL, yH, yL, wyB, partials);
    bnfinal2_kernel<<<dim3(C_), 256, 0, stream>>>(wyB, partials, x, gamma, beta, out);
}